// Round 4
// baseline (106.902 us; speedup 1.0000x reference)
//
#include <hip/hip_runtime.h>
#include <math.h>

// ---------------------------------------------------------------------------
// HQNN via trig-polynomial compression, row-packed v2f math.
//   E_w(h) = sum_{g in {0,1,2}^4} D_w[g] * prod_w f(g_w, h_w),
//   f(0,h)=1, f(1,h)=cos h, f(2,h)=sin h   (exact; entangler is batch-const)
// setup_D: 3 blocks (one per layer) gate-sim an 81-point grid, apply the 3x3
// inverse Vandermonde per wire dim.
// main kernel: 2 rows per thread packed into v2f lanes; contraction is
// 81 x (v_pk_mul + 4 v_pk_fma) with wave-uniform float4 coefficient loads
// (single base + immediate offsets; D spans 3888 B).
// ---------------------------------------------------------------------------

typedef float v2f __attribute__((ext_vector_type(2)));

__device__ __forceinline__ v2f splat2(float x) { return (v2f){x, x}; }

__device__ __forceinline__ v2f fast_tanh2(v2f x) {
    // tanh(x) = 1 - 2/(e^{2x}+1)
    float ua = __expf(2.0f * x.x);
    float ub = __expf(2.0f * x.y);
    v2f r = {__builtin_amdgcn_rcpf(ua + 1.0f), __builtin_amdgcn_rcpf(ub + 1.0f)};
    return splat2(-2.0f) * r + splat2(1.0f);   // v_pk_fma
}

// ------------------------- setup: gate simulation --------------------------

__device__ __forceinline__ void s_apply_rx(float2 st[16], int w, float c, float s) {
    const int bit = 1 << w;
#pragma unroll
    for (int b = 0; b < 16; ++b) {
        if (!(b & bit)) {
            float2 a0 = st[b];
            float2 a1 = st[b | bit];
            st[b].x       = fmaf(c, a0.x,  s * a1.y);
            st[b].y       = fmaf(c, a0.y, -s * a1.x);
            st[b | bit].x = fmaf(c, a1.x,  s * a0.y);
            st[b | bit].y = fmaf(c, a1.y, -s * a0.x);
        }
    }
}

__device__ __forceinline__ void s_apply_cnot(float2 st[16], int c, int t) {
    const int cb = 1 << c, tb = 1 << t;
#pragma unroll
    for (int b = 0; b < 16; ++b) {
        if ((b & cb) && !(b & tb)) {
            float2 tmp = st[b];
            st[b] = st[b | tb];
            st[b | tb] = tmp;
        }
    }
}

// grid = 3 blocks (one per layer), 128 threads each.
// D layout: D[(layer*81 + t)*4 + w], t = g0 + 3*g1 + 9*g2 + 27*g3.
__global__ void setup_D(const float* __restrict__ theta, float* __restrict__ D) {
    __shared__ float bufA[81 * 4];
    __shared__ float bufB[81 * 4];
    const int t = threadIdx.x;
    const int layer = blockIdx.x;

    if (t < 81) {
        const int g0 = t % 3, g1 = (t / 3) % 3, g2 = (t / 9) % 3, g3 = t / 27;
        const float H[3] = {0.0f, 1.5707963267948966f, 3.14159265358979323f};
        float h[4] = {H[g0], H[g1], H[g2], H[g3]};

        float2 st[16];
#pragma unroll
        for (int b = 0; b < 16; ++b) st[b] = make_float2(0.0f, 0.0f);
        st[0] = make_float2(1.0f, 0.0f);

        for (int w = 0; w < 4; ++w)
            s_apply_rx(st, w, __cosf(0.5f * h[w]), __sinf(0.5f * h[w]));
        for (int l = 0; l < 2; ++l) {
            for (int w = 0; w < 4; ++w) {
                float th = 0.5f * theta[layer * 8 + l * 4 + w];
                s_apply_rx(st, w, __cosf(th), __sinf(th));
            }
            for (int w = 0; w < 4; ++w)
                s_apply_cnot(st, w, (w + 1) & 3);
        }
        float pr[16], total = 0.0f;
#pragma unroll
        for (int b = 0; b < 16; ++b) {
            pr[b] = st[b].x * st[b].x + st[b].y * st[b].y;
            total += pr[b];
        }
        for (int w = 0; w < 4; ++w) {
            float s1 = 0.0f;
#pragma unroll
            for (int b = 0; b < 16; ++b)
                if ((b >> w) & 1) s1 += pr[b];
            bufA[t * 4 + w] = total - 2.0f * s1;
        }
    }
    __syncthreads();

    // inverse Vandermonde per wire dim:
    // a0 = (y0+y2)/2 ; a_cos = (y0-y2)/2 ; a_sin = y1 - (y0+y2)/2
    float* src = bufA;
    float* dst = bufB;
    int stride = 1;
    for (int d = 0; d < 4; ++d) {
        if (t < 81) {
            int digit = (t / stride) % 3;
            int base = t - digit * stride;
            for (int c = 0; c < 4; ++c) {
                float y0 = src[(base + 0 * stride) * 4 + c];
                float y1 = src[(base + 1 * stride) * 4 + c];
                float y2 = src[(base + 2 * stride) * 4 + c];
                float m = 0.5f * (y0 + y2);
                float a = (digit == 0) ? m : (digit == 1) ? 0.5f * (y0 - y2) : (y1 - m);
                dst[t * 4 + c] = a;
            }
        }
        __syncthreads();
        float* tmp = src; src = dst; dst = tmp;
        stride *= 3;
    }
    if (t < 81) {
        for (int c = 0; c < 4; ++c)
            D[(layer * 81 + t) * 4 + c] = src[t * 4 + c];
    }
}

// ------------------------------ main kernel --------------------------------

__global__ __launch_bounds__(256, 4)
void hqnn_kernel(const float4* __restrict__ x4,
                 const float4* __restrict__ D4,   // [3*81] float4 of coefs
                 const float* __restrict__ W0, const float* __restrict__ b0,
                 const float* __restrict__ W1, const float* __restrict__ b1,
                 const float* __restrict__ W2, const float* __restrict__ b2,
                 float4* __restrict__ out, int Bhalf) {
    int i = blockIdx.x * blockDim.x + threadIdx.x;
    if (i >= Bhalf) return;
    const int ra = i, rb = i + Bhalf;   // 2 rows/thread, both coalesced

    // ---- load both rows, pack as v2f {rowA, rowB} ----
    float4 a0 = x4[ra * 4 + 0], a1 = x4[ra * 4 + 1];
    float4 a2 = x4[ra * 4 + 2], a3 = x4[ra * 4 + 3];
    float4 bq0 = x4[rb * 4 + 0], bq1 = x4[rb * 4 + 1];
    float4 bq2 = x4[rb * 4 + 2], bq3 = x4[rb * 4 + 3];
    v2f xab[16] = {
        {a0.x, bq0.x}, {a0.y, bq0.y}, {a0.z, bq0.z}, {a0.w, bq0.w},
        {a1.x, bq1.x}, {a1.y, bq1.y}, {a1.z, bq1.z}, {a1.w, bq1.w},
        {a2.x, bq2.x}, {a2.y, bq2.y}, {a2.z, bq2.z}, {a2.w, bq2.w},
        {a3.x, bq3.x}, {a3.y, bq3.y}, {a3.z, bq3.z}, {a3.w, bq3.w}};

    // ---- layer-0 dense 16->4 (+tanh), packed ----
    v2f h[4];
#pragma unroll
    for (int j = 0; j < 4; ++j) {
        v2f acc = splat2(b0[j]);
#pragma unroll
        for (int k = 0; k < 16; ++k)
            acc = splat2(W0[k * 4 + j]) * xab[k] + acc;   // v_pk_fma, SGPR bcast
        h[j] = fast_tanh2(acc);
    }

#pragma unroll
    for (int layer = 0; layer < 3; ++layer) {
        // full-angle sincos per wire, both rows
        v2f c0 = {__cosf(h[0].x), __cosf(h[0].y)}, s0 = {__sinf(h[0].x), __sinf(h[0].y)};
        v2f c1 = {__cosf(h[1].x), __cosf(h[1].y)}, s1 = {__sinf(h[1].x), __sinf(h[1].y)};
        v2f c2 = {__cosf(h[2].x), __cosf(h[2].y)}, s2 = {__sinf(h[2].x), __sinf(h[2].y)};
        v2f c3 = {__cosf(h[3].x), __cosf(h[3].y)}, s3 = {__sinf(h[3].x), __sinf(h[3].y)};

        v2f one = splat2(1.0f);
        v2f p01[9] = {one, c0, s0, c1, c1 * c0, c1 * s0, s1, s1 * c0, s1 * s0};
        v2f p23[9] = {one, c2, s2, c3, c3 * c2, c3 * s2, s3, s3 * c2, s3 * s2};

        v2f E0 = {0.0f, 0.0f}, E1 = {0.0f, 0.0f};
        v2f E2 = {0.0f, 0.0f}, E3 = {0.0f, 0.0f};
#pragma unroll
        for (int j = 0; j < 9; ++j) {
#pragma unroll
            for (int ii = 0; ii < 9; ++ii) {
                float4 d = D4[layer * 81 + j * 9 + ii];  // wave-uniform, imm offset
                v2f T = p01[ii] * p23[j];                // v_pk_mul
                E0 = splat2(d.x) * T + E0;               // v_pk_fma (op_sel splat)
                E1 = splat2(d.y) * T + E1;
                E2 = splat2(d.z) * T + E2;
                E3 = splat2(d.w) * T + E3;
            }
        }

        if (layer < 2) {
            const float* W = (layer == 0) ? W1 : W2;
            const float* bb = (layer == 0) ? b1 : b2;
            v2f e[4] = {E0, E1, E2, E3};
#pragma unroll
            for (int j = 0; j < 4; ++j) {
                v2f acc = splat2(bb[j]);
#pragma unroll
                for (int k = 0; k < 4; ++k)
                    acc = splat2(W[k * 4 + j]) * e[k] + acc;
                h[j] = fast_tanh2(acc);
            }
        } else {
            out[ra] = make_float4(E0.x, E1.x, E2.x, E3.x);
            out[rb] = make_float4(E0.y, E1.y, E2.y, E3.y);
        }
    }
}

extern "C" void kernel_launch(void* const* d_in, const int* in_sizes, int n_in,
                              void* d_out, int out_size, void* d_ws, size_t ws_size,
                              hipStream_t stream) {
    const float* x  = (const float*)d_in[0];
    const float* th = (const float*)d_in[1];   // (3,2,4) = 24 floats
    const float* W0 = (const float*)d_in[2];
    const float* b0 = (const float*)d_in[3];
    const float* W1 = (const float*)d_in[4];
    const float* b1 = (const float*)d_in[5];
    const float* W2 = (const float*)d_in[6];
    const float* b2 = (const float*)d_in[7];
    float* out = (float*)d_out;
    float* D   = (float*)d_ws;                 // 3*81*4 floats = 3888 B

    int B = in_sizes[0] / 16;
    int Bhalf = B / 2;

    hipLaunchKernelGGL(setup_D, dim3(3), dim3(128), 0, stream, th, D);

    int block = 256;
    int grid = (Bhalf + block - 1) / block;
    hipLaunchKernelGGL(hqnn_kernel, dim3(grid), dim3(block), 0, stream,
                       (const float4*)x, (const float4*)D,
                       W0, b0, W1, b1, W2, b2,
                       (float4*)out, Bhalf);
}